// Round 4
// baseline (265.693 us; speedup 1.0000x reference)
//
#include <hip/hip_runtime.h>

typedef unsigned short u16;
typedef unsigned char  u8;
typedef unsigned int   u32;
typedef unsigned long long u64;

typedef short bf16x8 __attribute__((ext_vector_type(8)));
typedef float f32x4  __attribute__((ext_vector_type(4)));
typedef float f32x16 __attribute__((ext_vector_type(16)));

#define DEV __device__ __forceinline__

#if __has_builtin(__builtin_amdgcn_exp2f)
#define EXP2(x) __builtin_amdgcn_exp2f(x)
#else
#define EXP2(x) exp2f(x)
#endif

DEV u16 f2bf(float x) {
  u32 u = __builtin_bit_cast(u32, x);
  u32 r = (u + 0x7fffu + ((u >> 16) & 1u)) >> 16;
  return (u16)r;
}
DEV float bf2f(u16 h) {
  u32 u = ((u32)h) << 16;
  return __builtin_bit_cast(float, u);
}
DEV f32x4 mfma16(bf16x8 a, bf16x8 b, f32x4 c) {
  return __builtin_amdgcn_mfma_f32_16x16x32_bf16(a, b, c, 0, 0, 0);
}
DEV f32x16 mfma32(bf16x8 a, bf16x8 b, f32x16 c) {
  return __builtin_amdgcn_mfma_f32_32x32x16_bf16(a, b, c, 0, 0, 0);
}
// pack two f32 -> bf16x2 (RNE), no builtin on gfx950
DEV u32 cvtpk(float lo, float hi) {
  u32 r;
  asm("v_cvt_pk_bf16_f32 %0, %1, %2" : "=v"(r) : "v"(lo), "v"(hi));
  return r;
}
// swap: x_hi <-> y_lo across lane halves
DEV void pswap(u32& x, u32& y) {
  asm("v_permlane32_swap_b32 %0, %1" : "+v"(x), "+v"(y));
}
DEV bf16x8 mkfrag(u32 w0, u32 w1, u32 w2, u32 w3) {
  union { u32 w[4]; bf16x8 v; } u;
  u.w[0] = w0; u.w[1] = w1; u.w[2] = w2; u.w[3] = w3;
  return u.v;
}

#define GLDS(gptr, lptr)                                                  \
  __builtin_amdgcn_global_load_lds(                                       \
      (const __attribute__((address_space(1))) void*)(gptr),              \
      (__attribute__((address_space(3))) void*)(lptr), 16, 0, 0)

// ---------------------------------------------------------------------------
// 1) one-shot split: hidden -> hi/lo, qk_w -> hi/lo, v_w -> hi only
// ---------------------------------------------------------------------------
__global__ __launch_bounds__(256) void split3_kernel(
    const float* __restrict__ hid, const float* __restrict__ wq,
    const float* __restrict__ wv,
    u16* __restrict__ hHi, u16* __restrict__ hLo,
    u16* __restrict__ wqHi, u16* __restrict__ wqLo, u16* __restrict__ wvHi) {
  const int NH = 4194304, NW = 1048576;
  int i = blockIdx.x * 256 + threadIdx.x;
  if (i < NH) {
    float v = hid[i];
    u16 t = f2bf(v);
    hHi[i] = t;
    hLo[i] = f2bf(v - bf2f(t));
  } else if (i < NH + NW) {
    int j = i - NH;
    float v = wq[j];
    u16 t = f2bf(v);
    wqHi[j] = t;
    wqLo[j] = f2bf(v - bf2f(t));
  } else {
    int j = i - NH - NW;
    wvHi[j] = f2bf(wv[j]);
  }
}

// ---------------------------------------------------------------------------
// 2) ca[h][k] = sum_j W[h*64+j][k] * a[j]   (fp64)
// ---------------------------------------------------------------------------
__global__ __launch_bounds__(256) void ca_kernel(
    const float* __restrict__ W, const float* __restrict__ ha, double* __restrict__ ca) {
  int idx = blockIdx.x * 256 + threadIdx.x;  // 16 * 1024
  int h = idx >> 10, k = idx & 1023;
  double s = 0.0;
#pragma unroll 8
  for (int j = 0; j < 64; ++j)
    s += (double)W[(size_t)(h * 64 + j) * 1024 + k] * (double)ha[j];
  ca[idx] = s;
}

// ---------------------------------------------------------------------------
// 3) d[bh][l]: fp64 acc; 2 rows/wave reusing each ca load (halves L2 re-read)
// ---------------------------------------------------------------------------
__global__ __launch_bounds__(256) void d_kernel(
    const float* __restrict__ hid, const double* __restrict__ ca, float* __restrict__ dq) {
  const int row0 = blockIdx.x * 8 + (threadIdx.x >> 6) * 2;  // grid 512
  const int lane = threadIdx.x & 63;
  double a0[16], a1[16];
#pragma unroll
  for (int h = 0; h < 16; ++h) { a0[h] = 0.0; a1[h] = 0.0; }
  const float* hp = hid + (size_t)row0 * 1024;
  for (int k = lane; k < 1024; k += 64) {
    const double h0 = (double)hp[k];
    const double h1 = (double)hp[k + 1024];
#pragma unroll
    for (int h = 0; h < 16; ++h) {
      const double c = ca[h * 1024 + k];
      a0[h] += h0 * c;
      a1[h] += h1 * c;
    }
  }
#pragma unroll
  for (int h = 0; h < 16; ++h) {
    double v0 = a0[h], v1 = a1[h];
#pragma unroll
    for (int off = 32; off; off >>= 1) {
      v0 += __shfl_xor(v0, off, 64);
      v1 += __shfl_xor(v1, off, 64);
    }
    if (lane == 0) {
      const int b0 = row0 >> 11, l0 = row0 & 2047;
      dq[(size_t)(b0 * 16 + h) * 2048 + l0] = (float)v0;
      const int r1 = row0 + 1;
      dq[(size_t)((r1 >> 11) * 16 + h) * 2048 + (r1 & 2047)] = (float)v1;
    }
  }
}

// ---------------------------------------------------------------------------
// 4) dual-output GEMM, grid (64,8), 2 blocks/CU (unchanged)
// ---------------------------------------------------------------------------
__global__ __launch_bounds__(256, 2) void gemm_fused(
    const u16* __restrict__ hHi, const u16* __restrict__ hLo,
    const u16* __restrict__ wqHi, const u16* __restrict__ wqLo,
    const u16* __restrict__ wvHi,
    const float* __restrict__ qk_b, const float* __restrict__ v_b,
    u16* __restrict__ qkB, u16* __restrict__ vT, float* __restrict__ n2A) {
  constexpr int K = 1024;
  __shared__ u16 S[2][16384];
  const int tid = threadIdx.x, wave = tid >> 6, lane = tid & 63;
  const int quad = lane >> 4, lm = lane & 15;
  const int wr = wave >> 1, wc = wave & 1;
  const int m0 = blockIdx.x * 64, n0 = blockIdx.y * 128;
  const int ch = lane & 3, rA = lane >> 2;

  auto stage = [&](int kt, int buf) {
    const int k0 = kt * 32;
    const int rowA = wave * 16 + rA;
    GLDS(hHi + (size_t)(m0 + rowA) * K + k0 + ch * 8, &S[buf][0 + wave * 512]);
    GLDS(hLo + (size_t)(m0 + rowA) * K + k0 + ch * 8, &S[buf][2048 + wave * 512]);
#pragma unroll
    for (int it = 0; it < 2; ++it) {
      const int rb = wave * 2 + it;
      const int row = rb * 16 + rA;
      GLDS(wqHi + (size_t)(n0 + row) * K + k0 + ch * 8, &S[buf][4096 + rb * 512]);
      GLDS(wqLo + (size_t)(n0 + row) * K + k0 + ch * 8, &S[buf][8192 + rb * 512]);
      GLDS(wvHi + (size_t)(n0 + row) * K + k0 + ch * 8, &S[buf][12288 + rb * 512]);
    }
  };

  f32x4 aq[2][4], av[4][2];
#pragma unroll
  for (int i = 0; i < 2; ++i)
#pragma unroll
    for (int j = 0; j < 4; ++j) aq[i][j] = {0.f, 0.f, 0.f, 0.f};
#pragma unroll
  for (int i = 0; i < 4; ++i)
#pragma unroll
    for (int j = 0; j < 2; ++j) av[i][j] = {0.f, 0.f, 0.f, 0.f};

  stage(0, 0);
  __syncthreads();

  for (int kt = 0; kt < 32; ++kt) {
    const int cur = kt & 1;
    if (kt < 31) stage(kt + 1, cur ^ 1);

    bf16x8 a_h[2], a_l[2], b_h[4], b_l[4], w_h[4];
#pragma unroll
    for (int i = 0; i < 2; ++i) {
      a_h[i] = *(const bf16x8*)&S[cur][(wr * 32 + i * 16 + lm) * 32 + quad * 8];
      a_l[i] = *(const bf16x8*)&S[cur][2048 + (wr * 32 + i * 16 + lm) * 32 + quad * 8];
    }
#pragma unroll
    for (int j = 0; j < 4; ++j) {
      b_h[j] = *(const bf16x8*)&S[cur][4096 + (wc * 64 + j * 16 + lm) * 32 + quad * 8];
      b_l[j] = *(const bf16x8*)&S[cur][8192 + (wc * 64 + j * 16 + lm) * 32 + quad * 8];
      w_h[j] = *(const bf16x8*)&S[cur][12288 + (wc * 64 + j * 16 + lm) * 32 + quad * 8];
    }
#pragma unroll
    for (int i = 0; i < 2; ++i)
#pragma unroll
      for (int j = 0; j < 4; ++j) {
        aq[i][j] = mfma16(a_h[i], b_h[j], aq[i][j]);
        aq[i][j] = mfma16(a_h[i], b_l[j], aq[i][j]);
        aq[i][j] = mfma16(a_l[i], b_h[j], aq[i][j]);
      }
#pragma unroll
    for (int iv = 0; iv < 4; ++iv)
#pragma unroll
      for (int jv = 0; jv < 2; ++jv)
        av[iv][jv] = mfma16(w_h[iv], a_h[jv], av[iv][jv]);

    __syncthreads();
  }

  const int hidx = blockIdx.y * 2 + wc;
#pragma unroll
  for (int i = 0; i < 2; ++i) {
    float nn[4] = {0.f, 0.f, 0.f, 0.f};
#pragma unroll
    for (int j = 0; j < 4; ++j) {
      const int col = n0 + wc * 64 + j * 16 + lm;
      const float bv = qk_b[col];
#pragma unroll
      for (int r = 0; r < 4; ++r) {
        const int row = m0 + wr * 32 + i * 16 + quad * 4 + r;
        const float val = aq[i][j][r] + bv;
        qkB[(size_t)row * 1024 + col] = f2bf(val);
        nn[r] += val * val;
      }
    }
#pragma unroll
    for (int r = 0; r < 4; ++r)
#pragma unroll
      for (int off = 1; off < 16; off <<= 1) nn[r] += __shfl_xor(nn[r], off, 64);
    if (lm == 0) {
      const int row = m0 + wr * 32 + i * 16 + quad * 4;
      const int b = row >> 11, l = row & 2047;
      *(float4*)&n2A[(size_t)(b * 16 + hidx) * 2048 + l] =
          make_float4(nn[0], nn[1], nn[2], nn[3]);
    }
  }
#pragma unroll
  for (int iv = 0; iv < 4; ++iv)
#pragma unroll
    for (int r = 0; r < 4; ++r) {
      const int vcol = n0 + wc * 64 + iv * 16 + quad * 4 + r;
      const float bv = v_b[vcol];
#pragma unroll
      for (int jv = 0; jv < 2; ++jv) {
        const int tok = m0 + wr * 32 + jv * 16 + lm;
        vT[(size_t)vcol * 4096 + tok] = f2bf(av[iv][jv][r] + bv);
      }
    }
}

// ---------------------------------------------------------------------------
// 5) hash bits per (b,h): hq as bytes, hk packed as u64 per 64-key tile
// ---------------------------------------------------------------------------
__global__ __launch_bounds__(256) void bits_kernel(
    const float* __restrict__ n2A, const float* __restrict__ dq,
    const float* __restrict__ ha, u8* __restrict__ hqA, u64* __restrict__ hkM) {
  const int bh = blockIdx.x;
  const int tid = threadIdx.x;
  const int wave = tid >> 6, lane = tid & 63;
  __shared__ float red[4];
  const float* n2p = n2A + (size_t)bh * 2048;
  float4 v0 = ((const float4*)n2p)[tid];
  float4 v1 = ((const float4*)n2p)[tid + 256];
  float lmax = fmaxf(fmaxf(fmaxf(v0.x, v0.y), fmaxf(v0.z, v0.w)),
                     fmaxf(fmaxf(v1.x, v1.y), fmaxf(v1.z, v1.w)));
#pragma unroll
  for (int off = 1; off < 64; off <<= 1) lmax = fmaxf(lmax, __shfl_xor(lmax, off, 64));
  if (lane == 0) red[wave] = lmax;
  __syncthreads();
  const float maxn2 = fmaxf(fmaxf(red[0], red[1]), fmaxf(red[2], red[3]));
  const float s = 0.75f / fmaxf(sqrtf(maxn2), 1e-12f);
  const float a64 = ha[64], a65 = ha[65];
#pragma unroll
  for (int it = 0; it < 8; ++it) {
    const int l = it * 256 + tid;
    const float dv = dq[(size_t)bh * 2048 + l];
    const float n2 = n2p[l];
    const float nk2 = s * s * n2;
    const float hkdot = s * dv + (0.5f - nk2) * a64 + (0.5f - nk2 * nk2) * a65;
    hqA[(size_t)bh * 2048 + l] = (dv >= 0.f) ? 1 : 0;
    const u64 m = __ballot(hkdot >= 0.f);
    if (lane == 0) hkM[(size_t)bh * 32 + it * 4 + wave] = m;
  }
}

// ---------------------------------------------------------------------------
// 6) flash attention v8: 64 q per WAVE (two 32-q column groups sharing every
//    aK/aV LDS read -> LDS-read demand per unit work halved). 2-wave blocks
//    (128 q/block), grid 512, bh-fastest decode. Same verified v5/v7 pieces:
//    2-buffer K/V, one barrier/iter, fused exp->mask->pack, in-register P
//    transpose (cvtpk + permlane swap), VALU scalar l + final shfl_xor(32).
// ---------------------------------------------------------------------------
__global__ __launch_bounds__(128, 2) void attn_kernel(
    const u16* __restrict__ qkb, const u16* __restrict__ vT,
    const u8* __restrict__ hqA, const u64* __restrict__ hkM,
    float* __restrict__ out) {
  __shared__ u16 Ks[2][4096];   // [buf][key(64) x dim(64)], 16B-chunk XOR swizzle
  __shared__ u16 Vs[2][4096];   // [buf][dim(64) x key(64)], same swizzle

  const int id = blockIdx.x;    // bh fastest -> 4 distinct bh per XCD (L2-local)
  const int bh = id & 31, qt = id >> 5;   // qt 0..15 (128 queries each)
  const int b = bh >> 4, h = bh & 15;
  const int tid = threadIdx.x, wave = tid >> 6, lane = tid & 63;
  const int col = lane & 31;    // q column (within group) / A-frag row
  const int hf = lane >> 5;     // lane half (k-subchunk selector)
  const int ch7 = col & 7;
  const int r8 = lane >> 3, ch = lane & 7;
  const int q0 = qt * 128;
  const int tok0 = q0 + wave * 64 + col;   // q-group 0 token; group 1 = +32

  const u16* qbase = qkb + (size_t)b * 2048 * 1024 + h * 64;
  const u16* vtb = vT + (size_t)h * 64 * 4096 + b * 2048;  // row stride 4096
  const u64* hkp = hkM + (size_t)bh * 32;

  // Q B-frags straight from global, per q-group
  bf16x8 aQ[2][4];
  u32 hqx[2];
#pragma unroll
  for (int g = 0; g < 2; ++g) {
#pragma unroll
    for (int c = 0; c < 4; ++c)
      aQ[g][c] = *(const bf16x8*)(qbase +
          (size_t)(tok0 + g * 32) * 1024 + c * 16 + hf * 8);
    hqx[g] = hqA[(size_t)bh * 2048 + tok0 + g * 32] ? 0xFFFFFFFFu : 0u;
  }

  const int srow = wave * 32;   // this wave's 32-row staging slab
  auto stage = [&](int kt, int buf) {
#pragma unroll
    for (int i = 0; i < 4; ++i) {
      const int row = srow + i * 8 + r8;  // key row for K / dim row for V
      const int sw = (ch ^ (row & 7)) * 8;
      GLDS(qbase + (size_t)(kt * 64 + row) * 1024 + sw, &Ks[buf][(srow + i * 8) * 64]);
      GLDS(vtb + (size_t)row * 4096 + kt * 64 + sw, &Vs[buf][(srow + i * 8) * 64]);
    }
  };

  f32x16 acc[2][2];   // O^T accumulators [dim-block][q-group]
#pragma unroll
  for (int d = 0; d < 2; ++d)
#pragma unroll
    for (int g = 0; g < 2; ++g)
#pragma unroll
      for (int r = 0; r < 16; ++r) acc[d][g][r] = 0.f;
  float accL[2] = {0.f, 0.f};

  const float SCL = 0.18033688f;   // 0.125 * log2(e)
  const float M0 = -4.3280854f;    // -C*log2(e), C = 3

  u64 mk = hkp[0];
  stage(0, 0);
  __syncthreads();  // tile 0 staged (barrier drains vmcnt)

  for (int kt = 0; kt < 32; ++kt) {
    const int cur = kt & 1;
    if (kt < 31) stage(kt + 1, cur ^ 1);
    const u64 mk_next = (kt < 31) ? hkp[kt + 1] : 0ull;

    // per-half-aligned hk mask words: bit (kb*32 + pos) of (mk >> 4*hf)
    const u64 msh = mk >> (hf * 4);
    u32 mw[2];
    mw[0] = (u32)msh;
    mw[1] = (u32)(msh >> 32);

#pragma unroll
    for (int kb = 0; kb < 2; ++kb) {
      // K A-frags read ONCE, shared by both q-groups
      bf16x8 aK[4];
#pragma unroll
      for (int c = 0; c < 4; ++c)
        aK[c] = *(const bf16x8*)
            &Ks[cur][(kb * 32 + col) * 64 + (((c * 2 + hf) ^ ch7) * 8)];

      // S^T = K Q for both q-groups (independent chains -> ILP)
      f32x16 cs0, cs1;
#pragma unroll
      for (int r = 0; r < 16; ++r) { cs0[r] = 0.f; cs1[r] = 0.f; }
#pragma unroll
      for (int c = 0; c < 4; ++c) {
        cs0 = mfma32(aK[c], aQ[0][c], cs0);
        cs1 = mfma32(aK[c], aQ[1][c], cs1);
      }

      // exp -> mask -> pack -> permlane-transpose, per q-group
      bf16x8 fr[2][2];
#pragma unroll
      for (int g = 0; g < 2; ++g) {
        const u32 hw = mw[kb] ^ hqx[g];  // bit==1 -> hash mismatch -> p = 0
        u32 pk[8];
#pragma unroll
        for (int i = 0; i < 8; ++i) {
          const int r0 = 2 * i, r1 = 2 * i + 1;
          const int pos0 = (r0 & 3) + 8 * (r0 >> 2);
          const int pos1 = (r1 & 3) + 8 * (r1 >> 2);
          const float c0 = (g == 0) ? cs0[r0] : cs1[r0];
          const float c1 = (g == 0) ? cs0[r1] : cs1[r1];
          float p0 = EXP2(__builtin_fmaf(c0, SCL, M0));
          float p1 = EXP2(__builtin_fmaf(c1, SCL, M0));
          p0 = ((hw >> pos0) & 1u) ? 0.f : p0;
          p1 = ((hw >> pos1) & 1u) ? 0.f : p1;
          accL[g] += p0 + p1;
          pk[i] = cvtpk(p0, p1);
        }
        pswap(pk[0], pk[2]);
        pswap(pk[1], pk[3]);
        pswap(pk[4], pk[6]);
        pswap(pk[5], pk[7]);
        fr[g][0] = mkfrag(pk[0], pk[1], pk[2], pk[3]);  // keys kb*32+0..15
        fr[g][1] = mkfrag(pk[4], pk[5], pk[6], pk[7]);  // keys kb*32+16..31
      }

      // O^T += V^T P^T; each aV read shared by both q-groups
#pragma unroll
      for (int db = 0; db < 2; ++db) {
        const bf16x8 aV0 = *(const bf16x8*)
            &Vs[cur][(db * 32 + col) * 64 + ((((kb * 2 + 0) * 2 + hf) ^ ch7) * 8)];
        acc[db][0] = mfma32(aV0, fr[0][0], acc[db][0]);
        acc[db][1] = mfma32(aV0, fr[1][0], acc[db][1]);
        const bf16x8 aV1 = *(const bf16x8*)
            &Vs[cur][(db * 32 + col) * 64 + ((((kb * 2 + 1) * 2 + hf) ^ ch7) * 8)];
        acc[db][0] = mfma32(aV1, fr[0][1], acc[db][0]);
        acc[db][1] = mfma32(aV1, fr[1][1], acc[db][1]);
      }
    }

    mk = mk_next;
    __syncthreads();  // prev-tile reads done + next-tile staging drained
  }

  // l = sum over both lane-halves; lane owns column q = tok0 + g*32
#pragma unroll
  for (int g = 0; g < 2; ++g) {
    float lg = accL[g];
    lg += __shfl_xor(lg, 32);
    const float inv = 1.0f / lg;
    float* op = out + (size_t)(b * 2048 + tok0 + g * 32) * 1024 + h * 64 + hf * 4;
#pragma unroll
    for (int db = 0; db < 2; ++db)
#pragma unroll
      for (int gg = 0; gg < 4; ++gg) {
        float4 v4 = make_float4(acc[db][g][gg * 4 + 0] * inv,
                                acc[db][g][gg * 4 + 1] * inv,
                                acc[db][g][gg * 4 + 2] * inv,
                                acc[db][g][gg * 4 + 3] * inv);
        *(float4*)(op + db * 32 + gg * 8) = v4;  // d = db*32 + gg*8 + hf*4 + 0..3
      }
  }
}

// ---------------------------------------------------------------------------
extern "C" void kernel_launch(void* const* d_in, const int* in_sizes, int n_in,
                              void* d_out, int out_size, void* d_ws, size_t ws_size,
                              hipStream_t stream) {
  const float* hidden = (const float*)d_in[0];
  const float* qk_w   = (const float*)d_in[1];
  const float* qk_b   = (const float*)d_in[2];
  const float* v_w    = (const float*)d_in[3];
  const float* v_b    = (const float*)d_in[4];
  const float* hash_a = (const float*)d_in[5];
  float* out = (float*)d_out;

  char* base = (char*)d_ws;
  size_t off = 0;
  auto take = [&](size_t bytes) -> char* {
    char* r = base + off;
    off += (bytes + 255) & ~(size_t)255;
    return r;
  };
  const size_t NH = 4194304;  // B*L*D
  const size_t NW = 1048576;  // D*D
  u16* hHi  = (u16*)take(NH * 2);
  u16* hLo  = (u16*)take(NH * 2);
  u16* wqHi = (u16*)take(NW * 2);
  u16* wqLo = (u16*)take(NW * 2);
  u16* wvHi = (u16*)take(NW * 2);
  u16* qkB  = (u16*)take(NH * 2);
  u16* vT   = (u16*)take(NH * 2);
  double* ca = (double*)take(16 * 1024 * 8);
  float* dq  = (float*)take(65536 * 4);
  float* n2A = (float*)take(65536 * 4);
  u8* hqA = (u8*)take(65536);
  u64* hkM = (u64*)take(32 * 32 * 8);

  hipLaunchKernelGGL(split3_kernel, dim3((NH + 2 * NW) / 256), dim3(256), 0, stream,
                     hidden, qk_w, v_w, hHi, hLo, wqHi, wqLo, wvHi);
  hipLaunchKernelGGL(ca_kernel, dim3(64), dim3(256), 0, stream, qk_w, hash_a, ca);
  hipLaunchKernelGGL(d_kernel, dim3(512), dim3(256), 0, stream, hidden, ca, dq);
  hipLaunchKernelGGL(gemm_fused, dim3(64, 8), dim3(256), 0, stream,
                     hHi, hLo, wqHi, wqLo, wvHi, qk_b, v_b, qkB, vT, n2A);
  hipLaunchKernelGGL(bits_kernel, dim3(32), dim3(256), 0, stream, n2A, dq, hash_a, hqA, hkM);
  hipLaunchKernelGGL(attn_kernel, dim3(512), dim3(128), 0, stream, qkB, vT, hqA, hkM, out);
}

// Round 6
// 220.110 us; speedup vs baseline: 1.2071x; 1.2071x over previous
//
#include <hip/hip_runtime.h>

typedef unsigned short u16;
typedef unsigned char  u8;
typedef unsigned int   u32;
typedef unsigned long long u64;

typedef short bf16x8 __attribute__((ext_vector_type(8)));
typedef float f32x4  __attribute__((ext_vector_type(4)));
typedef float f32x16 __attribute__((ext_vector_type(16)));

#define DEV __device__ __forceinline__

#if __has_builtin(__builtin_amdgcn_exp2f)
#define EXP2(x) __builtin_amdgcn_exp2f(x)
#else
#define EXP2(x) exp2f(x)
#endif

DEV u16 f2bf(float x) {
  u32 u = __builtin_bit_cast(u32, x);
  u32 r = (u + 0x7fffu + ((u >> 16) & 1u)) >> 16;
  return (u16)r;
}
DEV float bf2f(u16 h) {
  u32 u = ((u32)h) << 16;
  return __builtin_bit_cast(float, u);
}
DEV f32x4 mfma16(bf16x8 a, bf16x8 b, f32x4 c) {
  return __builtin_amdgcn_mfma_f32_16x16x32_bf16(a, b, c, 0, 0, 0);
}
DEV f32x16 mfma32(bf16x8 a, bf16x8 b, f32x16 c) {
  return __builtin_amdgcn_mfma_f32_32x32x16_bf16(a, b, c, 0, 0, 0);
}
// pack two f32 -> bf16x2 (RNE), no builtin on gfx950
DEV u32 cvtpk(float lo, float hi) {
  u32 r;
  asm("v_cvt_pk_bf16_f32 %0, %1, %2" : "=v"(r) : "v"(lo), "v"(hi));
  return r;
}
// swap: x_hi <-> y_lo across lane halves
DEV void pswap(u32& x, u32& y) {
  asm("v_permlane32_swap_b32 %0, %1" : "+v"(x), "+v"(y));
}
DEV bf16x8 mkfrag(u32 w0, u32 w1, u32 w2, u32 w3) {
  union { u32 w[4]; bf16x8 v; } u;
  u.w[0] = w0; u.w[1] = w1; u.w[2] = w2; u.w[3] = w3;
  return u.v;
}

#define GLDS(gptr, lptr)                                                  \
  __builtin_amdgcn_global_load_lds(                                       \
      (const __attribute__((address_space(1))) void*)(gptr),              \
      (__attribute__((address_space(3))) void*)(lptr), 16, 0, 0)

// ---------------------------------------------------------------------------
// 1) one-shot split (vectorized x4): hidden -> hi/lo, qk_w -> hi/lo, v_w -> hi
// ---------------------------------------------------------------------------
__global__ __launch_bounds__(256) void split3_kernel(
    const float* __restrict__ hid, const float* __restrict__ wq,
    const float* __restrict__ wv,
    u16* __restrict__ hHi, u16* __restrict__ hLo,
    u16* __restrict__ wqHi, u16* __restrict__ wqLo, u16* __restrict__ wvHi) {
  const int NH4 = 1048576, NW4 = 262144;  // float4 counts
  int i = blockIdx.x * 256 + threadIdx.x;
  if (i < NH4) {
    float4 v = ((const float4*)hid)[i];
    ushort4 h, l;
    h.x = f2bf(v.x); l.x = f2bf(v.x - bf2f(h.x));
    h.y = f2bf(v.y); l.y = f2bf(v.y - bf2f(h.y));
    h.z = f2bf(v.z); l.z = f2bf(v.z - bf2f(h.z));
    h.w = f2bf(v.w); l.w = f2bf(v.w - bf2f(h.w));
    ((ushort4*)hHi)[i] = h;
    ((ushort4*)hLo)[i] = l;
  } else if (i < NH4 + NW4) {
    int j = i - NH4;
    float4 v = ((const float4*)wq)[j];
    ushort4 h, l;
    h.x = f2bf(v.x); l.x = f2bf(v.x - bf2f(h.x));
    h.y = f2bf(v.y); l.y = f2bf(v.y - bf2f(h.y));
    h.z = f2bf(v.z); l.z = f2bf(v.z - bf2f(h.z));
    h.w = f2bf(v.w); l.w = f2bf(v.w - bf2f(h.w));
    ((ushort4*)wqHi)[j] = h;
    ((ushort4*)wqLo)[j] = l;
  } else {
    int j = i - NH4 - NW4;
    float4 v = ((const float4*)wv)[j];
    ushort4 h;
    h.x = f2bf(v.x); h.y = f2bf(v.y); h.z = f2bf(v.z); h.w = f2bf(v.w);
    ((ushort4*)wvHi)[j] = h;
  }
}

// ---------------------------------------------------------------------------
// 2) ca[h][k] = sum_j W[h*64+j][k] * a[j]   (fp64)
// ---------------------------------------------------------------------------
__global__ __launch_bounds__(256) void ca_kernel(
    const float* __restrict__ W, const float* __restrict__ ha, double* __restrict__ ca) {
  int idx = blockIdx.x * 256 + threadIdx.x;  // 16 * 1024
  int h = idx >> 10, k = idx & 1023;
  double s = 0.0;
#pragma unroll 8
  for (int j = 0; j < 64; ++j)
    s += (double)W[(size_t)(h * 64 + j) * 1024 + k] * (double)ha[j];
  ca[idx] = s;
}

// ---------------------------------------------------------------------------
// 3) d[bh][l]: fp64 acc; 2 rows/wave reusing each ca load (halves L2 re-read)
// ---------------------------------------------------------------------------
__global__ __launch_bounds__(256) void d_kernel(
    const float* __restrict__ hid, const double* __restrict__ ca, float* __restrict__ dq) {
  const int row0 = blockIdx.x * 8 + (threadIdx.x >> 6) * 2;  // grid 512
  const int lane = threadIdx.x & 63;
  double a0[16], a1[16];
#pragma unroll
  for (int h = 0; h < 16; ++h) { a0[h] = 0.0; a1[h] = 0.0; }
  const float* hp = hid + (size_t)row0 * 1024;
  for (int k = lane; k < 1024; k += 64) {
    const double h0 = (double)hp[k];
    const double h1 = (double)hp[k + 1024];
#pragma unroll
    for (int h = 0; h < 16; ++h) {
      const double c = ca[h * 1024 + k];
      a0[h] += h0 * c;
      a1[h] += h1 * c;
    }
  }
#pragma unroll
  for (int h = 0; h < 16; ++h) {
    double v0 = a0[h], v1 = a1[h];
#pragma unroll
    for (int off = 32; off; off >>= 1) {
      v0 += __shfl_xor(v0, off, 64);
      v1 += __shfl_xor(v1, off, 64);
    }
    if (lane == 0) {
      const int b0 = row0 >> 11, l0 = row0 & 2047;
      dq[(size_t)(b0 * 16 + h) * 2048 + l0] = (float)v0;
      const int r1 = row0 + 1;
      dq[(size_t)((r1 >> 11) * 16 + h) * 2048 + (r1 & 2047)] = (float)v1;
    }
  }
}

// ---------------------------------------------------------------------------
// 4) dual-output GEMM, grid (64,8), 2 blocks/CU (unchanged)
// ---------------------------------------------------------------------------
__global__ __launch_bounds__(256, 2) void gemm_fused(
    const u16* __restrict__ hHi, const u16* __restrict__ hLo,
    const u16* __restrict__ wqHi, const u16* __restrict__ wqLo,
    const u16* __restrict__ wvHi,
    const float* __restrict__ qk_b, const float* __restrict__ v_b,
    u16* __restrict__ qkB, u16* __restrict__ vT, float* __restrict__ n2A) {
  constexpr int K = 1024;
  __shared__ u16 S[2][16384];
  const int tid = threadIdx.x, wave = tid >> 6, lane = tid & 63;
  const int quad = lane >> 4, lm = lane & 15;
  const int wr = wave >> 1, wc = wave & 1;
  const int m0 = blockIdx.x * 64, n0 = blockIdx.y * 128;
  const int ch = lane & 3, rA = lane >> 2;

  auto stage = [&](int kt, int buf) {
    const int k0 = kt * 32;
    const int rowA = wave * 16 + rA;
    GLDS(hHi + (size_t)(m0 + rowA) * K + k0 + ch * 8, &S[buf][0 + wave * 512]);
    GLDS(hLo + (size_t)(m0 + rowA) * K + k0 + ch * 8, &S[buf][2048 + wave * 512]);
#pragma unroll
    for (int it = 0; it < 2; ++it) {
      const int rb = wave * 2 + it;
      const int row = rb * 16 + rA;
      GLDS(wqHi + (size_t)(n0 + row) * K + k0 + ch * 8, &S[buf][4096 + rb * 512]);
      GLDS(wqLo + (size_t)(n0 + row) * K + k0 + ch * 8, &S[buf][8192 + rb * 512]);
      GLDS(wvHi + (size_t)(n0 + row) * K + k0 + ch * 8, &S[buf][12288 + rb * 512]);
    }
  };

  f32x4 aq[2][4], av[4][2];
#pragma unroll
  for (int i = 0; i < 2; ++i)
#pragma unroll
    for (int j = 0; j < 4; ++j) aq[i][j] = {0.f, 0.f, 0.f, 0.f};
#pragma unroll
  for (int i = 0; i < 4; ++i)
#pragma unroll
    for (int j = 0; j < 2; ++j) av[i][j] = {0.f, 0.f, 0.f, 0.f};

  stage(0, 0);
  __syncthreads();

  for (int kt = 0; kt < 32; ++kt) {
    const int cur = kt & 1;
    if (kt < 31) stage(kt + 1, cur ^ 1);

    bf16x8 a_h[2], a_l[2], b_h[4], b_l[4], w_h[4];
#pragma unroll
    for (int i = 0; i < 2; ++i) {
      a_h[i] = *(const bf16x8*)&S[cur][(wr * 32 + i * 16 + lm) * 32 + quad * 8];
      a_l[i] = *(const bf16x8*)&S[cur][2048 + (wr * 32 + i * 16 + lm) * 32 + quad * 8];
    }
#pragma unroll
    for (int j = 0; j < 4; ++j) {
      b_h[j] = *(const bf16x8*)&S[cur][4096 + (wc * 64 + j * 16 + lm) * 32 + quad * 8];
      b_l[j] = *(const bf16x8*)&S[cur][8192 + (wc * 64 + j * 16 + lm) * 32 + quad * 8];
      w_h[j] = *(const bf16x8*)&S[cur][12288 + (wc * 64 + j * 16 + lm) * 32 + quad * 8];
    }
#pragma unroll
    for (int i = 0; i < 2; ++i)
#pragma unroll
      for (int j = 0; j < 4; ++j) {
        aq[i][j] = mfma16(a_h[i], b_h[j], aq[i][j]);
        aq[i][j] = mfma16(a_h[i], b_l[j], aq[i][j]);
        aq[i][j] = mfma16(a_l[i], b_h[j], aq[i][j]);
      }
#pragma unroll
    for (int iv = 0; iv < 4; ++iv)
#pragma unroll
      for (int jv = 0; jv < 2; ++jv)
        av[iv][jv] = mfma16(w_h[iv], a_h[jv], av[iv][jv]);

    __syncthreads();
  }

  const int hidx = blockIdx.y * 2 + wc;
#pragma unroll
  for (int i = 0; i < 2; ++i) {
    float nn[4] = {0.f, 0.f, 0.f, 0.f};
#pragma unroll
    for (int j = 0; j < 4; ++j) {
      const int col = n0 + wc * 64 + j * 16 + lm;
      const float bv = qk_b[col];
#pragma unroll
      for (int r = 0; r < 4; ++r) {
        const int row = m0 + wr * 32 + i * 16 + quad * 4 + r;
        const float val = aq[i][j][r] + bv;
        qkB[(size_t)row * 1024 + col] = f2bf(val);
        nn[r] += val * val;
      }
    }
#pragma unroll
    for (int r = 0; r < 4; ++r)
#pragma unroll
      for (int off = 1; off < 16; off <<= 1) nn[r] += __shfl_xor(nn[r], off, 64);
    if (lm == 0) {
      const int row = m0 + wr * 32 + i * 16 + quad * 4;
      const int b = row >> 11, l = row & 2047;
      *(float4*)&n2A[(size_t)(b * 16 + hidx) * 2048 + l] =
          make_float4(nn[0], nn[1], nn[2], nn[3]);
    }
  }
#pragma unroll
  for (int iv = 0; iv < 4; ++iv)
#pragma unroll
    for (int r = 0; r < 4; ++r) {
      const int vcol = n0 + wc * 64 + iv * 16 + quad * 4 + r;
      const float bv = v_b[vcol];
#pragma unroll
      for (int jv = 0; jv < 2; ++jv) {
        const int tok = m0 + wr * 32 + jv * 16 + lm;
        vT[(size_t)vcol * 4096 + tok] = f2bf(av[iv][jv][r] + bv);
      }
    }
}

// ---------------------------------------------------------------------------
// 5) hash bits per (b,h): hq as bytes, hk packed as u64 per 64-key tile
// ---------------------------------------------------------------------------
__global__ __launch_bounds__(256) void bits_kernel(
    const float* __restrict__ n2A, const float* __restrict__ dq,
    const float* __restrict__ ha, u8* __restrict__ hqA, u64* __restrict__ hkM) {
  const int bh = blockIdx.x;
  const int tid = threadIdx.x;
  const int wave = tid >> 6, lane = tid & 63;
  __shared__ float red[4];
  const float* n2p = n2A + (size_t)bh * 2048;
  float4 v0 = ((const float4*)n2p)[tid];
  float4 v1 = ((const float4*)n2p)[tid + 256];
  float lmax = fmaxf(fmaxf(fmaxf(v0.x, v0.y), fmaxf(v0.z, v0.w)),
                     fmaxf(fmaxf(v1.x, v1.y), fmaxf(v1.z, v1.w)));
#pragma unroll
  for (int off = 1; off < 64; off <<= 1) lmax = fmaxf(lmax, __shfl_xor(lmax, off, 64));
  if (lane == 0) red[wave] = lmax;
  __syncthreads();
  const float maxn2 = fmaxf(fmaxf(red[0], red[1]), fmaxf(red[2], red[3]));
  const float s = 0.75f / fmaxf(sqrtf(maxn2), 1e-12f);
  const float a64 = ha[64], a65 = ha[65];
#pragma unroll
  for (int it = 0; it < 8; ++it) {
    const int l = it * 256 + tid;
    const float dv = dq[(size_t)bh * 2048 + l];
    const float n2 = n2p[l];
    const float nk2 = s * s * n2;
    const float hkdot = s * dv + (0.5f - nk2) * a64 + (0.5f - nk2 * nk2) * a65;
    hqA[(size_t)bh * 2048 + l] = (dv >= 0.f) ? 1 : 0;
    const u64 m = __ballot(hkdot >= 0.f);
    if (lane == 0) hkM[(size_t)bh * 32 + it * 4 + wave] = m;
  }
}

// ---------------------------------------------------------------------------
// 6) flash attention v5 (round-1 verified, 65.3us): 32x32x16 MFMA, S^T layout,
//    in-register P transpose (cvtpk + permlane swap), 128 q/block (32 q/wave),
//    grid 512 = 2 blocks/CU, dbuf GLDS staging w/ XOR swizzle, 1 barrier/iter.
//    LDS traffic per wave per iter: 16x ds_read_b128 only (K+V tiles);
//    P never touches LDS; l is a per-lane scalar + final shfl_xor(32).
// ---------------------------------------------------------------------------
__global__ __launch_bounds__(256, 2) void attn_kernel(
    const u16* __restrict__ qkb, const u16* __restrict__ vT,
    const u8* __restrict__ hqA, const u64* __restrict__ hkM,
    float* __restrict__ out) {
  __shared__ u16 Ks[2][4096];   // [buf][key(64) x dim(64)], 16B-chunk XOR swizzle
  __shared__ u16 Vs[2][4096];   // [buf][dim(64) x key(64)], same swizzle

  const int id = blockIdx.x;    // XCD-friendly decode: bh fastest -> 4 bh/XCD
  const int bh = id & 31, qt = id >> 5;   // qt 0..15 (128 queries each)
  const int b = bh >> 4, h = bh & 15;
  const int tid = threadIdx.x, wave = tid >> 6, lane = tid & 63;
  const int col = lane & 31;    // q column within wave / row within A-frags
  const int hf = lane >> 5;     // lane half (k-subchunk selector)
  const int ch7 = col & 7;
  const int r8 = lane >> 3, ch = lane & 7;
  const int q0 = qt * 128;
  const int token = q0 + wave * 32 + col;

  const u16* qbase = qkb + (size_t)b * 2048 * 1024 + h * 64;
  const u16* vtb = vT + (size_t)h * 64 * 4096 + b * 2048;  // row stride 4096
  const u64* hkp = hkM + (size_t)bh * 32;

  // Q B-frags straight from global: B[k=d][col=q], chunk c covers d=c*16+hf*8..+7
  bf16x8 aQ[4];
#pragma unroll
  for (int c = 0; c < 4; ++c)
    aQ[c] = *(const bf16x8*)(qbase + (size_t)token * 1024 + c * 16 + hf * 8);
  const u32 hqx = hqA[(size_t)bh * 2048 + token] ? 0xFFFFFFFFu : 0u;

  const int srow = wave * 16;   // this wave's 16-row staging slab
  auto stage = [&](int kt, int buf) {
#pragma unroll
    for (int i = 0; i < 2; ++i) {
      const int row = srow + i * 8 + r8;  // key row for K / dim row for V
      const int sw = (ch ^ (row & 7)) * 8;
      GLDS(qbase + (size_t)(kt * 64 + row) * 1024 + sw, &Ks[buf][(srow + i * 8) * 64]);
      GLDS(vtb + (size_t)row * 4096 + kt * 64 + sw, &Vs[buf][(srow + i * 8) * 64]);
    }
  };

  f32x16 acc[2];
#pragma unroll
  for (int d = 0; d < 2; ++d)
#pragma unroll
    for (int r = 0; r < 16; ++r) acc[d][r] = 0.f;
  float accL = 0.f;

  const float SCL = 0.18033688f;   // 0.125 * log2(e)
  const float M0 = -4.3280854f;    // -C*log2(e), C = 3

  u64 mk = hkp[0];
  stage(0, 0);
  __syncthreads();  // tile 0 staged (barrier drains vmcnt)

  for (int kt = 0; kt < 32; ++kt) {
    const int cur = kt & 1;
    if (kt < 31) stage(kt + 1, cur ^ 1);
    const u64 mk_next = (kt < 31) ? hkp[kt + 1] : 0ull;

    // per-half-aligned hk mask words: bit (kb*32 + pos) of (mk >> 4*hf)
    const u64 msh = mk >> (hf * 4);
    u32 mw[2];
    mw[0] = (u32)msh;
    mw[1] = (u32)(msh >> 32);

#pragma unroll
    for (int kb = 0; kb < 2; ++kb) {
      const u32 hw = mw[kb] ^ hqx;  // bit==1 -> hash mismatch -> p = 0
      // S^T[key][q] for 32 keys: A = K rows, B = Q cols, 4 chunks over d=64
      f32x16 cs;
#pragma unroll
      for (int r = 0; r < 16; ++r) cs[r] = 0.f;
      __builtin_amdgcn_s_setprio(1);
#pragma unroll
      for (int c = 0; c < 4; ++c) {
        const bf16x8 aK = *(const bf16x8*)
            &Ks[cur][(kb * 32 + col) * 64 + (((c * 2 + hf) ^ ch7) * 8)];
        cs = mfma32(aK, aQ[c], cs);
      }
      __builtin_amdgcn_s_setprio(0);

      // p = 2^(s*SCL + M0), zeroed on hash mismatch; accL accumulates l
      float pv[16];
#pragma unroll
      for (int r = 0; r < 16; ++r) {
        const int pos = (r & 3) + 8 * (r >> 2);  // C-layout key offset (+4*hf)
        float p = EXP2(__builtin_fmaf(cs[r], SCL, M0));
        p = ((hw >> pos) & 1u) ? 0.f : p;
        accL += p;
        pv[r] = p;
      }
      // pack -> bf16 pairs; permlane32_swap assembles PV B-frags in-register
      u32 pk[8];
#pragma unroll
      for (int i = 0; i < 8; ++i) pk[i] = cvtpk(pv[2 * i], pv[2 * i + 1]);
      pswap(pk[0], pk[2]);
      pswap(pk[1], pk[3]);
      pswap(pk[4], pk[6]);
      pswap(pk[5], pk[7]);
      const bf16x8 fr0 = mkfrag(pk[0], pk[1], pk[2], pk[3]);  // keys kb*32+0..15
      const bf16x8 fr1 = mkfrag(pk[4], pk[5], pk[6], pk[7]);  // keys kb*32+16..31

      // O^T[d][q] += V^T P^T  (A = V^T rows d, B = P^T frags)
      __builtin_amdgcn_s_setprio(1);
#pragma unroll
      for (int db = 0; db < 2; ++db) {
        const bf16x8 aV0 = *(const bf16x8*)
            &Vs[cur][(db * 32 + col) * 64 + ((((kb * 2 + 0) * 2 + hf) ^ ch7) * 8)];
        acc[db] = mfma32(aV0, fr0, acc[db]);
        const bf16x8 aV1 = *(const bf16x8*)
            &Vs[cur][(db * 32 + col) * 64 + ((((kb * 2 + 1) * 2 + hf) ^ ch7) * 8)];
        acc[db] = mfma32(aV1, fr1, acc[db]);
      }
      __builtin_amdgcn_s_setprio(0);
    }

    mk = mk_next;
    __syncthreads();  // prev-tile reads done + next-tile staging drained
  }

  // l = sum over both lane-halves; lane owns column q = token
  accL += __shfl_xor(accL, 32);
  const float inv = 1.0f / accL;
  float* op = out + (size_t)(b * 2048 + token) * 1024 + h * 64 + hf * 4;
#pragma unroll
  for (int db = 0; db < 2; ++db)
#pragma unroll
    for (int g = 0; g < 4; ++g) {
      float4 v4 = make_float4(acc[db][g * 4 + 0] * inv, acc[db][g * 4 + 1] * inv,
                              acc[db][g * 4 + 2] * inv, acc[db][g * 4 + 3] * inv);
      *(float4*)(op + db * 32 + g * 8) = v4;  // d = db*32 + g*8 + hf*4 + 0..3
    }
}

// ---------------------------------------------------------------------------
extern "C" void kernel_launch(void* const* d_in, const int* in_sizes, int n_in,
                              void* d_out, int out_size, void* d_ws, size_t ws_size,
                              hipStream_t stream) {
  const float* hidden = (const float*)d_in[0];
  const float* qk_w   = (const float*)d_in[1];
  const float* qk_b   = (const float*)d_in[2];
  const float* v_w    = (const float*)d_in[3];
  const float* v_b    = (const float*)d_in[4];
  const float* hash_a = (const float*)d_in[5];
  float* out = (float*)d_out;

  char* base = (char*)d_ws;
  size_t off = 0;
  auto take = [&](size_t bytes) -> char* {
    char* r = base + off;
    off += (bytes + 255) & ~(size_t)255;
    return r;
  };
  const size_t NH = 4194304;  // B*L*D
  const size_t NW = 1048576;  // D*D
  u16* hHi  = (u16*)take(NH * 2);
  u16* hLo  = (u16*)take(NH * 2);
  u16* wqHi = (u16*)take(NW * 2);
  u16* wqLo = (u16*)take(NW * 2);
  u16* wvHi = (u16*)take(NW * 2);
  u16* qkB  = (u16*)take(NH * 2);
  u16* vT   = (u16*)take(NH * 2);
  double* ca = (double*)take(16 * 1024 * 8);
  float* dq  = (float*)take(65536 * 4);
  float* n2A = (float*)take(65536 * 4);
  u8* hqA = (u8*)take(65536);
  u64* hkM = (u64*)take(32 * 32 * 8);

  hipLaunchKernelGGL(split3_kernel, dim3(6144), dim3(256), 0, stream,
                     hidden, qk_w, v_w, hHi, hLo, wqHi, wqLo, wvHi);
  hipLaunchKernelGGL(ca_kernel, dim3(64), dim3(256), 0, stream, qk_w, hash_a, ca);
  hipLaunchKernelGGL(d_kernel, dim3(512), dim3(256), 0, stream, hidden, ca, dq);
  hipLaunchKernelGGL(gemm_fused, dim3(64, 8), dim3(256), 0, stream,
                     hHi, hLo, wqHi, wqLo, wvHi, qk_b, v_b, qkB, vT, n2A);
  hipLaunchKernelGGL(bits_kernel, dim3(32), dim3(256), 0, stream, n2A, dq, hash_a, hqA, hkM);
  hipLaunchKernelGGL(attn_kernel, dim3(512), dim3(256), 0, stream, qkB, vT, hqA, hkM, out);
}

// Round 7
// 217.719 us; speedup vs baseline: 1.2203x; 1.0110x over previous
//
#include <hip/hip_runtime.h>

typedef unsigned short u16;
typedef unsigned char  u8;
typedef unsigned int   u32;
typedef unsigned long long u64;

typedef short bf16x8 __attribute__((ext_vector_type(8)));
typedef float f32x4  __attribute__((ext_vector_type(4)));
typedef float f32x16 __attribute__((ext_vector_type(16)));

#define DEV __device__ __forceinline__

#if __has_builtin(__builtin_amdgcn_exp2f)
#define EXP2(x) __builtin_amdgcn_exp2f(x)
#else
#define EXP2(x) exp2f(x)
#endif

DEV u16 f2bf(float x) {
  u32 u = __builtin_bit_cast(u32, x);
  u32 r = (u + 0x7fffu + ((u >> 16) & 1u)) >> 16;
  return (u16)r;
}
DEV float bf2f(u16 h) {
  u32 u = ((u32)h) << 16;
  return __builtin_bit_cast(float, u);
}
DEV f32x4 mfma16(bf16x8 a, bf16x8 b, f32x4 c) {
  return __builtin_amdgcn_mfma_f32_16x16x32_bf16(a, b, c, 0, 0, 0);
}
DEV f32x16 mfma32(bf16x8 a, bf16x8 b, f32x16 c) {
  return __builtin_amdgcn_mfma_f32_32x32x16_bf16(a, b, c, 0, 0, 0);
}
// pack two f32 -> bf16x2 (RNE), no builtin on gfx950
DEV u32 cvtpk(float lo, float hi) {
  u32 r;
  asm("v_cvt_pk_bf16_f32 %0, %1, %2" : "=v"(r) : "v"(lo), "v"(hi));
  return r;
}
// swap: x_hi <-> y_lo across lane halves
DEV void pswap(u32& x, u32& y) {
  asm("v_permlane32_swap_b32 %0, %1" : "+v"(x), "+v"(y));
}
DEV bf16x8 mkfrag(u32 w0, u32 w1, u32 w2, u32 w3) {
  union { u32 w[4]; bf16x8 v; } u;
  u.w[0] = w0; u.w[1] = w1; u.w[2] = w2; u.w[3] = w3;
  return u.v;
}

#define GLDS(gptr, lptr)                                                  \
  __builtin_amdgcn_global_load_lds(                                       \
      (const __attribute__((address_space(1))) void*)(gptr),              \
      (__attribute__((address_space(3))) void*)(lptr), 16, 0, 0)

// ---------------------------------------------------------------------------
// 1) one-shot split (vectorized x4): hidden -> hi/lo, qk_w -> hi/lo, v_w -> hi
// ---------------------------------------------------------------------------
__global__ __launch_bounds__(256) void split3_kernel(
    const float* __restrict__ hid, const float* __restrict__ wq,
    const float* __restrict__ wv,
    u16* __restrict__ hHi, u16* __restrict__ hLo,
    u16* __restrict__ wqHi, u16* __restrict__ wqLo, u16* __restrict__ wvHi) {
  const int NH4 = 1048576, NW4 = 262144;  // float4 counts
  int i = blockIdx.x * 256 + threadIdx.x;
  if (i < NH4) {
    float4 v = ((const float4*)hid)[i];
    ushort4 h, l;
    h.x = f2bf(v.x); l.x = f2bf(v.x - bf2f(h.x));
    h.y = f2bf(v.y); l.y = f2bf(v.y - bf2f(h.y));
    h.z = f2bf(v.z); l.z = f2bf(v.z - bf2f(h.z));
    h.w = f2bf(v.w); l.w = f2bf(v.w - bf2f(h.w));
    ((ushort4*)hHi)[i] = h;
    ((ushort4*)hLo)[i] = l;
  } else if (i < NH4 + NW4) {
    int j = i - NH4;
    float4 v = ((const float4*)wq)[j];
    ushort4 h, l;
    h.x = f2bf(v.x); l.x = f2bf(v.x - bf2f(h.x));
    h.y = f2bf(v.y); l.y = f2bf(v.y - bf2f(h.y));
    h.z = f2bf(v.z); l.z = f2bf(v.z - bf2f(h.z));
    h.w = f2bf(v.w); l.w = f2bf(v.w - bf2f(h.w));
    ((ushort4*)wqHi)[j] = h;
    ((ushort4*)wqLo)[j] = l;
  } else {
    int j = i - NH4 - NW4;
    float4 v = ((const float4*)wv)[j];
    ushort4 h;
    h.x = f2bf(v.x); h.y = f2bf(v.y); h.z = f2bf(v.z); h.w = f2bf(v.w);
    ((ushort4*)wvHi)[j] = h;
  }
}

// ---------------------------------------------------------------------------
// 2) ca[h][k] = sum_j W[h*64+j][k] * a[j]   (fp64)
// ---------------------------------------------------------------------------
__global__ __launch_bounds__(256) void ca_kernel(
    const float* __restrict__ W, const float* __restrict__ ha, double* __restrict__ ca) {
  int idx = blockIdx.x * 256 + threadIdx.x;  // 16 * 1024
  int h = idx >> 10, k = idx & 1023;
  double s = 0.0;
#pragma unroll 8
  for (int j = 0; j < 64; ++j)
    s += (double)W[(size_t)(h * 64 + j) * 1024 + k] * (double)ha[j];
  ca[idx] = s;
}

// ---------------------------------------------------------------------------
// 3) d[bh][l]: fp64 acc; 2 rows/wave reusing each ca load (halves L2 re-read)
// ---------------------------------------------------------------------------
__global__ __launch_bounds__(256) void d_kernel(
    const float* __restrict__ hid, const double* __restrict__ ca, float* __restrict__ dq) {
  const int row0 = blockIdx.x * 8 + (threadIdx.x >> 6) * 2;  // grid 512
  const int lane = threadIdx.x & 63;
  double a0[16], a1[16];
#pragma unroll
  for (int h = 0; h < 16; ++h) { a0[h] = 0.0; a1[h] = 0.0; }
  const float* hp = hid + (size_t)row0 * 1024;
  for (int k = lane; k < 1024; k += 64) {
    const double h0 = (double)hp[k];
    const double h1 = (double)hp[k + 1024];
#pragma unroll
    for (int h = 0; h < 16; ++h) {
      const double c = ca[h * 1024 + k];
      a0[h] += h0 * c;
      a1[h] += h1 * c;
    }
  }
#pragma unroll
  for (int h = 0; h < 16; ++h) {
    double v0 = a0[h], v1 = a1[h];
#pragma unroll
    for (int off = 32; off; off >>= 1) {
      v0 += __shfl_xor(v0, off, 64);
      v1 += __shfl_xor(v1, off, 64);
    }
    if (lane == 0) {
      const int b0 = row0 >> 11, l0 = row0 & 2047;
      dq[(size_t)(b0 * 16 + h) * 2048 + l0] = (float)v0;
      const int r1 = row0 + 1;
      dq[(size_t)((r1 >> 11) * 16 + h) * 2048 + (r1 & 2047)] = (float)v1;
    }
  }
}

// ---------------------------------------------------------------------------
// 4) dual-output GEMM, grid (64,8), 2 blocks/CU (unchanged)
// ---------------------------------------------------------------------------
__global__ __launch_bounds__(256, 2) void gemm_fused(
    const u16* __restrict__ hHi, const u16* __restrict__ hLo,
    const u16* __restrict__ wqHi, const u16* __restrict__ wqLo,
    const u16* __restrict__ wvHi,
    const float* __restrict__ qk_b, const float* __restrict__ v_b,
    u16* __restrict__ qkB, u16* __restrict__ vT, float* __restrict__ n2A) {
  constexpr int K = 1024;
  __shared__ u16 S[2][16384];
  const int tid = threadIdx.x, wave = tid >> 6, lane = tid & 63;
  const int quad = lane >> 4, lm = lane & 15;
  const int wr = wave >> 1, wc = wave & 1;
  const int m0 = blockIdx.x * 64, n0 = blockIdx.y * 128;
  const int ch = lane & 3, rA = lane >> 2;

  auto stage = [&](int kt, int buf) {
    const int k0 = kt * 32;
    const int rowA = wave * 16 + rA;
    GLDS(hHi + (size_t)(m0 + rowA) * K + k0 + ch * 8, &S[buf][0 + wave * 512]);
    GLDS(hLo + (size_t)(m0 + rowA) * K + k0 + ch * 8, &S[buf][2048 + wave * 512]);
#pragma unroll
    for (int it = 0; it < 2; ++it) {
      const int rb = wave * 2 + it;
      const int row = rb * 16 + rA;
      GLDS(wqHi + (size_t)(n0 + row) * K + k0 + ch * 8, &S[buf][4096 + rb * 512]);
      GLDS(wqLo + (size_t)(n0 + row) * K + k0 + ch * 8, &S[buf][8192 + rb * 512]);
      GLDS(wvHi + (size_t)(n0 + row) * K + k0 + ch * 8, &S[buf][12288 + rb * 512]);
    }
  };

  f32x4 aq[2][4], av[4][2];
#pragma unroll
  for (int i = 0; i < 2; ++i)
#pragma unroll
    for (int j = 0; j < 4; ++j) aq[i][j] = {0.f, 0.f, 0.f, 0.f};
#pragma unroll
  for (int i = 0; i < 4; ++i)
#pragma unroll
    for (int j = 0; j < 2; ++j) av[i][j] = {0.f, 0.f, 0.f, 0.f};

  stage(0, 0);
  __syncthreads();

  for (int kt = 0; kt < 32; ++kt) {
    const int cur = kt & 1;
    if (kt < 31) stage(kt + 1, cur ^ 1);

    bf16x8 a_h[2], a_l[2], b_h[4], b_l[4], w_h[4];
#pragma unroll
    for (int i = 0; i < 2; ++i) {
      a_h[i] = *(const bf16x8*)&S[cur][(wr * 32 + i * 16 + lm) * 32 + quad * 8];
      a_l[i] = *(const bf16x8*)&S[cur][2048 + (wr * 32 + i * 16 + lm) * 32 + quad * 8];
    }
#pragma unroll
    for (int j = 0; j < 4; ++j) {
      b_h[j] = *(const bf16x8*)&S[cur][4096 + (wc * 64 + j * 16 + lm) * 32 + quad * 8];
      b_l[j] = *(const bf16x8*)&S[cur][8192 + (wc * 64 + j * 16 + lm) * 32 + quad * 8];
      w_h[j] = *(const bf16x8*)&S[cur][12288 + (wc * 64 + j * 16 + lm) * 32 + quad * 8];
    }
#pragma unroll
    for (int i = 0; i < 2; ++i)
#pragma unroll
      for (int j = 0; j < 4; ++j) {
        aq[i][j] = mfma16(a_h[i], b_h[j], aq[i][j]);
        aq[i][j] = mfma16(a_h[i], b_l[j], aq[i][j]);
        aq[i][j] = mfma16(a_l[i], b_h[j], aq[i][j]);
      }
#pragma unroll
    for (int iv = 0; iv < 4; ++iv)
#pragma unroll
      for (int jv = 0; jv < 2; ++jv)
        av[iv][jv] = mfma16(w_h[iv], a_h[jv], av[iv][jv]);

    __syncthreads();
  }

  const int hidx = blockIdx.y * 2 + wc;
#pragma unroll
  for (int i = 0; i < 2; ++i) {
    float nn[4] = {0.f, 0.f, 0.f, 0.f};
#pragma unroll
    for (int j = 0; j < 4; ++j) {
      const int col = n0 + wc * 64 + j * 16 + lm;
      const float bv = qk_b[col];
#pragma unroll
      for (int r = 0; r < 4; ++r) {
        const int row = m0 + wr * 32 + i * 16 + quad * 4 + r;
        const float val = aq[i][j][r] + bv;
        qkB[(size_t)row * 1024 + col] = f2bf(val);
        nn[r] += val * val;
      }
    }
#pragma unroll
    for (int r = 0; r < 4; ++r)
#pragma unroll
      for (int off = 1; off < 16; off <<= 1) nn[r] += __shfl_xor(nn[r], off, 64);
    if (lm == 0) {
      const int row = m0 + wr * 32 + i * 16 + quad * 4;
      const int b = row >> 11, l = row & 2047;
      *(float4*)&n2A[(size_t)(b * 16 + hidx) * 2048 + l] =
          make_float4(nn[0], nn[1], nn[2], nn[3]);
    }
  }
#pragma unroll
  for (int iv = 0; iv < 4; ++iv)
#pragma unroll
    for (int r = 0; r < 4; ++r) {
      const int vcol = n0 + wc * 64 + iv * 16 + quad * 4 + r;
      const float bv = v_b[vcol];
#pragma unroll
      for (int jv = 0; jv < 2; ++jv) {
        const int tok = m0 + wr * 32 + jv * 16 + lm;
        vT[(size_t)vcol * 4096 + tok] = f2bf(av[iv][jv][r] + bv);
      }
    }
}

// ---------------------------------------------------------------------------
// 5) hash bits per (b,h): hq as bytes, hk packed as u64 per 64-key tile
// ---------------------------------------------------------------------------
__global__ __launch_bounds__(256) void bits_kernel(
    const float* __restrict__ n2A, const float* __restrict__ dq,
    const float* __restrict__ ha, u8* __restrict__ hqA, u64* __restrict__ hkM) {
  const int bh = blockIdx.x;
  const int tid = threadIdx.x;
  const int wave = tid >> 6, lane = tid & 63;
  __shared__ float red[4];
  const float* n2p = n2A + (size_t)bh * 2048;
  float4 v0 = ((const float4*)n2p)[tid];
  float4 v1 = ((const float4*)n2p)[tid + 256];
  float lmax = fmaxf(fmaxf(fmaxf(v0.x, v0.y), fmaxf(v0.z, v0.w)),
                     fmaxf(fmaxf(v1.x, v1.y), fmaxf(v1.z, v1.w)));
#pragma unroll
  for (int off = 1; off < 64; off <<= 1) lmax = fmaxf(lmax, __shfl_xor(lmax, off, 64));
  if (lane == 0) red[wave] = lmax;
  __syncthreads();
  const float maxn2 = fmaxf(fmaxf(red[0], red[1]), fmaxf(red[2], red[3]));
  const float s = 0.75f / fmaxf(sqrtf(maxn2), 1e-12f);
  const float a64 = ha[64], a65 = ha[65];
#pragma unroll
  for (int it = 0; it < 8; ++it) {
    const int l = it * 256 + tid;
    const float dv = dq[(size_t)bh * 2048 + l];
    const float n2 = n2p[l];
    const float nk2 = s * s * n2;
    const float hkdot = s * dv + (0.5f - nk2) * a64 + (0.5f - nk2 * nk2) * a65;
    hqA[(size_t)bh * 2048 + l] = (dv >= 0.f) ? 1 : 0;
    const u64 m = __ballot(hkdot >= 0.f);
    if (lane == 0) hkM[(size_t)bh * 32 + it * 4 + wave] = m;
  }
}

// ---------------------------------------------------------------------------
// 6) flash attention v11: r1-verified per-tile body, but TWO k-tiles per
//    barrier (128 keys/sync). LDS 64 KB/block (2 pairs x K+V), still 2
//    blocks/CU. Stage next PAIR while computing current pair; one
//    __syncthreads per pair -> barrier-drain count halved (32 -> 16).
// ---------------------------------------------------------------------------
__global__ __launch_bounds__(256, 2) void attn_kernel(
    const u16* __restrict__ qkb, const u16* __restrict__ vT,
    const u8* __restrict__ hqA, const u64* __restrict__ hkM,
    float* __restrict__ out) {
  __shared__ u16 Ks[2][2][4096];  // [pair-buf][tile-in-pair][key(64) x dim(64)]
  __shared__ u16 Vs[2][2][4096];  // [pair-buf][tile-in-pair][dim(64) x key(64)]

  const int id = blockIdx.x;    // XCD-friendly decode: bh fastest -> 4 bh/XCD
  const int bh = id & 31, qt = id >> 5;   // qt 0..15 (128 queries each)
  const int b = bh >> 4, h = bh & 15;
  const int tid = threadIdx.x, wave = tid >> 6, lane = tid & 63;
  const int col = lane & 31;    // q column within wave / row within A-frags
  const int hf = lane >> 5;     // lane half (k-subchunk selector)
  const int ch7 = col & 7;
  const int r8 = lane >> 3, ch = lane & 7;
  const int q0 = qt * 128;
  const int token = q0 + wave * 32 + col;

  const u16* qbase = qkb + (size_t)b * 2048 * 1024 + h * 64;
  const u16* vtb = vT + (size_t)h * 64 * 4096 + b * 2048;  // row stride 4096
  const u64* hkp = hkM + (size_t)bh * 32;

  // Q B-frags straight from global: B[k=d][col=q], chunk c covers d=c*16+hf*8..+7
  bf16x8 aQ[4];
#pragma unroll
  for (int c = 0; c < 4; ++c)
    aQ[c] = *(const bf16x8*)(qbase + (size_t)token * 1024 + c * 16 + hf * 8);
  const u32 hqx = hqA[(size_t)bh * 2048 + token] ? 0xFFFFFFFFu : 0u;

  const int srow = wave * 16;   // this wave's 16-row staging slab
  auto stage = [&](int kt, int buf, int sub) {
#pragma unroll
    for (int i = 0; i < 2; ++i) {
      const int row = srow + i * 8 + r8;  // key row for K / dim row for V
      const int sw = (ch ^ (row & 7)) * 8;
      GLDS(qbase + (size_t)(kt * 64 + row) * 1024 + sw,
           &Ks[buf][sub][(srow + i * 8) * 64]);
      GLDS(vtb + (size_t)row * 4096 + kt * 64 + sw,
           &Vs[buf][sub][(srow + i * 8) * 64]);
    }
  };

  f32x16 acc[2];
#pragma unroll
  for (int d = 0; d < 2; ++d)
#pragma unroll
    for (int r = 0; r < 16; ++r) acc[d][r] = 0.f;
  float accL = 0.f;

  const float SCL = 0.18033688f;   // 0.125 * log2(e)
  const float M0 = -4.3280854f;    // -C*log2(e), C = 3

  stage(0, 0, 0);
  stage(1, 0, 1);
  __syncthreads();  // pair 0 staged (barrier drains vmcnt)

  for (int kt2 = 0; kt2 < 16; ++kt2) {
    const int cur = kt2 & 1;
    if (kt2 < 15) {
      stage(kt2 * 2 + 2, cur ^ 1, 0);
      stage(kt2 * 2 + 3, cur ^ 1, 1);
    }

#pragma unroll
    for (int sub = 0; sub < 2; ++sub) {
      const u64 mk = hkp[kt2 * 2 + sub];
      // per-half-aligned hk mask words: bit (kb*32 + pos) of (mk >> 4*hf)
      const u64 msh = mk >> (hf * 4);
      u32 mw[2];
      mw[0] = (u32)msh;
      mw[1] = (u32)(msh >> 32);

#pragma unroll
      for (int kb = 0; kb < 2; ++kb) {
        const u32 hw = mw[kb] ^ hqx;  // bit==1 -> hash mismatch -> p = 0
        // S^T[key][q] for 32 keys: A = K rows, B = Q cols, 4 chunks over d=64
        f32x16 cs;
#pragma unroll
        for (int r = 0; r < 16; ++r) cs[r] = 0.f;
        __builtin_amdgcn_s_setprio(1);
#pragma unroll
        for (int c = 0; c < 4; ++c) {
          const bf16x8 aK = *(const bf16x8*)
              &Ks[cur][sub][(kb * 32 + col) * 64 + (((c * 2 + hf) ^ ch7) * 8)];
          cs = mfma32(aK, aQ[c], cs);
        }
        __builtin_amdgcn_s_setprio(0);

        // p = 2^(s*SCL + M0), zeroed on hash mismatch; accL accumulates l
        float pv[16];
#pragma unroll
        for (int r = 0; r < 16; ++r) {
          const int pos = (r & 3) + 8 * (r >> 2);  // C-layout key offset (+4*hf)
          float p = EXP2(__builtin_fmaf(cs[r], SCL, M0));
          p = ((hw >> pos) & 1u) ? 0.f : p;
          accL += p;
          pv[r] = p;
        }
        // pack -> bf16 pairs; permlane32_swap assembles PV B-frags in-register
        u32 pk[8];
#pragma unroll
        for (int i = 0; i < 8; ++i) pk[i] = cvtpk(pv[2 * i], pv[2 * i + 1]);
        pswap(pk[0], pk[2]);
        pswap(pk[1], pk[3]);
        pswap(pk[4], pk[6]);
        pswap(pk[5], pk[7]);
        const bf16x8 fr0 = mkfrag(pk[0], pk[1], pk[2], pk[3]);  // keys kb*32+0..15
        const bf16x8 fr1 = mkfrag(pk[4], pk[5], pk[6], pk[7]);  // keys kb*32+16..31

        // O^T[d][q] += V^T P^T  (A = V^T rows d, B = P^T frags)
        __builtin_amdgcn_s_setprio(1);
#pragma unroll
        for (int db = 0; db < 2; ++db) {
          const bf16x8 aV0 = *(const bf16x8*)
              &Vs[cur][sub][(db * 32 + col) * 64 + ((((kb * 2 + 0) * 2 + hf) ^ ch7) * 8)];
          acc[db] = mfma32(aV0, fr0, acc[db]);
          const bf16x8 aV1 = *(const bf16x8*)
              &Vs[cur][sub][(db * 32 + col) * 64 + ((((kb * 2 + 1) * 2 + hf) ^ ch7) * 8)];
          acc[db] = mfma32(aV1, fr1, acc[db]);
        }
        __builtin_amdgcn_s_setprio(0);
      }
    }

    __syncthreads();  // pair reads done + next-pair staging drained
  }

  // l = sum over both lane-halves; lane owns column q = token
  accL += __shfl_xor(accL, 32);
  const float inv = 1.0f / accL;
  float* op = out + (size_t)(b * 2048 + token) * 1024 + h * 64 + hf * 4;
#pragma unroll
  for (int db = 0; db < 2; ++db)
#pragma unroll
    for (int g = 0; g < 4; ++g) {
      float4 v4 = make_float4(acc[db][g * 4 + 0] * inv, acc[db][g * 4 + 1] * inv,
                              acc[db][g * 4 + 2] * inv, acc[db][g * 4 + 3] * inv);
      *(float4*)(op + db * 32 + g * 8) = v4;  // d = db*32 + g*8 + hf*4 + 0..3
    }
}

// ---------------------------------------------------------------------------
extern "C" void kernel_launch(void* const* d_in, const int* in_sizes, int n_in,
                              void* d_out, int out_size, void* d_ws, size_t ws_size,
                              hipStream_t stream) {
  const float* hidden = (const float*)d_in[0];
  const float* qk_w   = (const float*)d_in[1];
  const float* qk_b   = (const float*)d_in[2];
  const float* v_w    = (const float*)d_in[3];
  const float* v_b    = (const float*)d_in[4];
  const float* hash_a = (const float*)d_in[5];
  float* out = (float*)d_out;

  char* base = (char*)d_ws;
  size_t off = 0;
  auto take = [&](size_t bytes) -> char* {
    char* r = base + off;
    off += (bytes + 255) & ~(size_t)255;
    return r;
  };
  const size_t NH = 4194304;  // B*L*D
  const size_t NW = 1048576;  // D*D
  u16* hHi  = (u16*)take(NH * 2);
  u16* hLo  = (u16*)take(NH * 2);
  u16* wqHi = (u16*)take(NW * 2);
  u16* wqLo = (u16*)take(NW * 2);
  u16* wvHi = (u16*)take(NW * 2);
  u16* qkB  = (u16*)take(NH * 2);
  u16* vT   = (u16*)take(NH * 2);
  double* ca = (double*)take(16 * 1024 * 8);
  float* dq  = (float*)take(65536 * 4);
  float* n2A = (float*)take(65536 * 4);
  u8* hqA = (u8*)take(65536);
  u64* hkM = (u64*)take(32 * 32 * 8);

  hipLaunchKernelGGL(split3_kernel, dim3(6144), dim3(256), 0, stream,
                     hidden, qk_w, v_w, hHi, hLo, wqHi, wqLo, wvHi);
  hipLaunchKernelGGL(ca_kernel, dim3(64), dim3(256), 0, stream, qk_w, hash_a, ca);
  hipLaunchKernelGGL(d_kernel, dim3(512), dim3(256), 0, stream, hidden, ca, dq);
  hipLaunchKernelGGL(gemm_fused, dim3(64, 8), dim3(256), 0, stream,
                     hHi, hLo, wqHi, wqLo, wvHi, qk_b, v_b, qkB, vT, n2A);
  hipLaunchKernelGGL(bits_kernel, dim3(32), dim3(256), 0, stream, n2A, dq, hash_a, hqA, hkM);
  hipLaunchKernelGGL(attn_kernel, dim3(512), dim3(256), 0, stream, qkB, vT, hqA, hkM, out);
}